// Round 5
// baseline (699.205 us; speedup 1.0000x reference)
//
#include <hip/hip_runtime.h>
#include <math.h>

// Problem constants (MixtureLowRankRNN)
#define HIDDEN_ 1024
#define RANK_ 4
#define INPUT_ 16
#define T_ 1024
#define BATCH_ 32

// --- scan kernel geometry: 2 batches per block, 256 threads per batch ---
#define SCAN_THREADS_ 512
#define TPB_ 256                      // threads per batch half
#define NWAVES_H_ (TPB_ / 64)         // 4 waves per half
#define EPT_ (HIDDEN_ / TPB_)         // 4 h-elements per thread
#define CH_ 64                        // x-steps per LDS-staged chunk (4KB/half)
#define NCH_ (T_ / CH_)               // 16 chunks

#define PRE_BLOCKS_ 2048
#define ROWS_ (BATCH_ * T_)              // 32768 rows of x
#define PASSES_ (ROWS_ / PRE_BLOCKS_)    // 16

typedef float f32x4 __attribute__((ext_vector_type(4)));

__device__ __forceinline__ float fast_exp2(float x) {
#if defined(__has_builtin)
#if __has_builtin(__builtin_amdgcn_exp2f)
    return __builtin_amdgcn_exp2f(x);
#else
    return exp2f(x);
#endif
#else
    return exp2f(x);
#endif
}

__device__ __forceinline__ float fast_rcp(float x) {
#if defined(__has_builtin)
#if __has_builtin(__builtin_amdgcn_rcpf)
    return __builtin_amdgcn_rcpf(x);
#else
    return 1.0f / x;
#endif
#else
    return 1.0f / x;
#endif
}

// tanh(x) = 1 - 2/(exp(2x)+1); exp(2x) = 2^(2*log2(e)*x).
__device__ __forceinline__ float tanh_fast(float x) {
    float e = fast_exp2(x * 2.885390081777926815f); // 2*log2(e)
    return fmaf(-2.0f, fast_rcp(e + 1.0f), 1.0f);
}

// One DPP reduce step: v += dpp_mov(v, ctrl) with old=0, bound_ctrl=1
#define DPP_ADD(v, ctrl)                                                          \
    do {                                                                          \
        int _t = __builtin_amdgcn_update_dpp(0, __float_as_int(v), (ctrl), 0xf,   \
                                             0xf, true);                          \
        (v) += __int_as_float(_t);                                                \
    } while (0)

// ---------------------------------------------------------------------------
// Kernel 1: u[row, h] = kin * sum_i I[h,i] * x[row,i]   (row = b*T + t)
// ---------------------------------------------------------------------------
__global__ __launch_bounds__(TPB_, 2) void precompute_u(
    const float* __restrict__ x,     // [ROWS_, 16]
    const float* __restrict__ imat,  // [H, 16]
    float* __restrict__ u)           // [ROWS_, H]
{
    const int tid = threadIdx.x;
    const int bid = blockIdx.x;
    const float kin = 0.1f;

    float Ir[4][INPUT_];
#pragma unroll
    for (int r = 0; r < 4; ++r) {
        const float* ip = imat + (4 * tid + r) * INPUT_;
#pragma unroll
        for (int q = 0; q < 4; ++q) {
            const float4 v = *(const float4*)(ip + 4 * q);
            Ir[r][q*4+0] = kin * v.x; Ir[r][q*4+1] = kin * v.y;
            Ir[r][q*4+2] = kin * v.z; Ir[r][q*4+3] = kin * v.w;
        }
    }

    for (int p = 0; p < PASSES_; ++p) {
        const int row = p * PRE_BLOCKS_ + bid;
        const float* xr = x + (size_t)row * INPUT_;
        float xv[INPUT_];
#pragma unroll
        for (int q = 0; q < 4; ++q) {
            const float4 v = ((const float4*)xr)[q];   // wave-uniform
            xv[q*4+0] = v.x; xv[q*4+1] = v.y; xv[q*4+2] = v.z; xv[q*4+3] = v.w;
        }
        float4 acc;
        float a[4];
#pragma unroll
        for (int r = 0; r < 4; ++r) {
            float s0 = xv[0] * Ir[r][0];
            float s1 = xv[1] * Ir[r][1];
#pragma unroll
            for (int i = 2; i < INPUT_; i += 2) {
                s0 = fmaf(xv[i],     Ir[r][i],     s0);
                s1 = fmaf(xv[i + 1], Ir[r][i + 1], s1);
            }
            a[r] = s0 + s1;
        }
        acc.x = a[0]; acc.y = a[1]; acc.z = a[2]; acc.w = a[3];
        *(float4*)(u + (size_t)row * HIDDEN_ + 4 * tid) = acc;  // coalesced
    }
}

// ---------------------------------------------------------------------------
// Kernel 2: serial scan — TWO batches per block (512 thr, 8 waves).
// At 1 wave/SIMD every dependent-op latency is exposed (measured: ~700 cy
// stall/step invariant across R0-R4 regardless of barrier type or memory
// path). 2 waves/SIMD lets the two batches' issue streams interleave and
// hide each other's VALU/trans/DPP latencies.
//   y_t = 0.9*y_{t-1} + [krec*s_t ; kin*x_t],  s_t = n^T tanh(h_{t-1}),
//   h_t = 0.9*h_{t-1} + (krec*m) s_t + u_t     (u precomputed).
// ---------------------------------------------------------------------------
__global__ __launch_bounds__(SCAN_THREADS_)
__attribute__((amdgpu_waves_per_eu(2, 2)))
void rnn_scan_kernel(
    const float* __restrict__ x,     // [B, T, 16]
    const float* __restrict__ m,     // [H, 4]
    const float* __restrict__ n,     // [H, 4]
    const float* __restrict__ u,     // [B, T, H] precomputed
    float* __restrict__ out)         // [B, T, 20]
{
    const int tid  = threadIdx.x;
    const int half = tid >> 8;           // 0 or 1 -> which batch
    const int tidh = tid & (TPB_ - 1);   // thread id within the batch half
    const int wv   = tidh >> 6;          // wave index within half (0..3)
    const int lane = tid & 63;
    const int b    = blockIdx.x * 2 + half;

    const float kd   = 0.9f;                      // 1 - ALPHA
    const float krec = 0.1f * (500.0f / 1024.0f); // ALPHA * BASE_SCALE / HIDDEN

    float h[EPT_];
    float mrs[EPT_][RANK_];    // krec * m row
    float nr[EPT_][RANK_];
#pragma unroll
    for (int j = 0; j < EPT_; ++j) {
        const int hidx = tidh * EPT_ + j;
        h[j] = 0.0f;
        const float4 mv = *(const float4*)(m + hidx * RANK_);
        mrs[j][0] = krec * mv.x; mrs[j][1] = krec * mv.y;
        mrs[j][2] = krec * mv.z; mrs[j][3] = krec * mv.w;
        const float4 nv = *(const float4*)(n + hidx * RANK_);
        nr[j][0] = nv.x; nr[j][1] = nv.y; nr[j][2] = nv.z; nr[j][3] = nv.w;
    }

    // per-half LDS: cross-wave partials (parity dbuf) + staged x chunks (dbuf)
    __shared__ float4 part[2][2][NWAVES_H_];
    __shared__ float xs[2][2][CH_ * INPUT_];   // 2 halves x 2 x 4KB

    const float* xb = x + (size_t)b * T_ * INPUT_;
    const float* ub = u + (size_t)b * T_ * HIDDEN_ + tidh * EPT_;
    float* ob = out + (size_t)b * T_ * (RANK_ + INPUT_);

    // Prologue: stage x chunk 0 -> xs[half][0]; chunk 1 in regs; prefetch u[0..3].
    {
        float4 c0 = *(const float4*)(xb + tidh * 4);
        *(float4*)&xs[half][0][tidh * 4] = c0;
    }
    float4 xstage = *(const float4*)(xb + CH_ * INPUT_ + tidh * 4);

    float4 upf[4];
#pragma unroll
    for (int k = 0; k < 4; ++k)
        upf[k] = *(const float4*)(ub + (size_t)k * HIDDEN_);

    float y = 0.0f;  // output accumulator (tidh < 20)
    const int yoff = (tidh >= 4 && tidh < 20) ? (tidh - 4) : 0;

#pragma unroll 4
    for (int t = 0; t < T_; ++t) {
        // --- tanh(h) + rank partials (VALU only) ---
        float th[EPT_];
#pragma unroll
        for (int j = 0; j < EPT_; ++j) th[j] = tanh_fast(h[j]);

        float p0 = th[0] * nr[0][0], p1 = th[0] * nr[0][1];
        float p2 = th[0] * nr[0][2], p3 = th[0] * nr[0][3];
#pragma unroll
        for (int j = 1; j < EPT_; ++j) {
            p0 = fmaf(th[j], nr[j][0], p0);
            p1 = fmaf(th[j], nr[j][1], p1);
            p2 = fmaf(th[j], nr[j][2], p2);
            p3 = fmaf(th[j], nr[j][3], p3);
        }

        // --- wave reduce via DPP, level-major for ILP across 4 ranks ---
        DPP_ADD(p0, 0x111); DPP_ADD(p1, 0x111); DPP_ADD(p2, 0x111); DPP_ADD(p3, 0x111);
        DPP_ADD(p0, 0x112); DPP_ADD(p1, 0x112); DPP_ADD(p2, 0x112); DPP_ADD(p3, 0x112);
        DPP_ADD(p0, 0x114); DPP_ADD(p1, 0x114); DPP_ADD(p2, 0x114); DPP_ADD(p3, 0x114);
        DPP_ADD(p0, 0x118); DPP_ADD(p1, 0x118); DPP_ADD(p2, 0x118); DPP_ADD(p3, 0x118);
        DPP_ADD(p0, 0x142); DPP_ADD(p1, 0x142); DPP_ADD(p2, 0x142); DPP_ADD(p3, 0x142);
        DPP_ADD(p0, 0x143); DPP_ADD(p1, 0x143); DPP_ADD(p2, 0x143); DPP_ADD(p3, 0x143);

        if (lane == 63) part[half][t & 1][wv] = make_float4(p0, p1, p2, p3);

        // Raw barrier: LDS-visibility wait ONLY (no vmcnt drain — u prefetch,
        // x staging loads and y stores stay in flight across steps).
        asm volatile("s_waitcnt lgkmcnt(0)\n\ts_barrier" ::: "memory");

        // --- x chunk staging for the y path (every 64 steps) ---
        if ((t & (CH_ - 1)) == 0) {
            const int c = t >> 6;
            *(float4*)&xs[half][(c + 1) & 1][tidh * 4] = xstage;   // chunk c+1
            const int cl = (c + 2 < NCH_) ? (c + 2) : (NCH_ - 1);
            xstage = *(const float4*)(xb + cl * CH_ * INPUT_ + tidh * 4);
        }

        // --- read cross-wave partials + this step's u + y-drive x ---
        const float4 q0 = part[half][t & 1][0];
        const float4 q1 = part[half][t & 1][1];
        const float4 q2 = part[half][t & 1][2];
        const float4 q3 = part[half][t & 1][3];
        const float xyv = xs[half][(t >> 6) & 1][(t & 63) * INPUT_ + yoff];

        const float4 uv = upf[t & 3];   // prefetched 4 steps ago
        {   // refill slot with u[t+4] (clamped dummy re-read near the tail)
            const int tn = (t + 4 < T_) ? (t + 4) : t;
            upf[t & 3] = *(const float4*)(ub + (size_t)tn * HIDDEN_);
        }

        // --- combine partials -> s ---
        const float s0 = (q0.x + q1.x) + (q2.x + q3.x);
        const float s1 = (q0.y + q1.y) + (q2.y + q3.y);
        const float s2 = (q0.z + q1.z) + (q2.z + q3.z);
        const float s3 = (q0.w + q1.w) + (q2.w + q3.w);

        // --- h <- kd*h + mrs@s + u_t  (short tree from s) ---
        const float uq[4] = {uv.x, uv.y, uv.z, uv.w};
#pragma unroll
        for (int j = 0; j < EPT_; ++j) {
            float a01 = fmaf(s1, mrs[j][1], fmaf(s0, mrs[j][0], uq[j]));
            float a23 = fmaf(s3, mrs[j][3], s2 * mrs[j][2]);
            h[j] = fmaf(kd, h[j], a01 + a23);
        }

        // --- y_t = kd*y_{t-1} + [krec*s ; kin*x_t]  (lanes 0..19 of each half's wave 0) ---
        if (tidh < 20) {
            float drive;
            if (tidh < 4) {
                float sv = (tidh == 0) ? s0 : (tidh == 1) ? s1 : (tidh == 2) ? s2 : s3;
                drive = krec * sv;
            } else {
                drive = 0.1f * xyv;   // kin
            }
            y = fmaf(kd, y, drive);
            ob[t * 20 + tidh] = y;   // fire-and-forget: never drained in-loop
        }
    }
}

// ---------------------------------------------------------------------------
// Fallback (no workspace): R2-style single kernel computing I@x in-loop.
// ---------------------------------------------------------------------------
__global__ __launch_bounds__(TPB_)
__attribute__((amdgpu_waves_per_eu(1, 1)))
void rnn_scan_fallback(
    const float* __restrict__ x, const float* __restrict__ m,
    const float* __restrict__ n, const float* __restrict__ imat,
    float* __restrict__ out)
{
    const int b    = blockIdx.x;
    const int tid  = threadIdx.x;
    const int wave = tid >> 6;
    const int lane = tid & 63;
    const float kd = 0.9f, krec = 0.1f * (500.0f / 1024.0f), kin = 0.1f;

    float h[EPT_], mrs[EPT_][RANK_], nr[EPT_][RANK_], Irs[EPT_][INPUT_];
#pragma unroll
    for (int j = 0; j < EPT_; ++j) {
        const int hidx = tid * EPT_ + j;
        h[j] = 0.0f;
        const float4 mv = *(const float4*)(m + hidx * RANK_);
        mrs[j][0] = krec * mv.x; mrs[j][1] = krec * mv.y;
        mrs[j][2] = krec * mv.z; mrs[j][3] = krec * mv.w;
        const float4 nv = *(const float4*)(n + hidx * RANK_);
        nr[j][0] = nv.x; nr[j][1] = nv.y; nr[j][2] = nv.z; nr[j][3] = nv.w;
#pragma unroll
        for (int q = 0; q < 4; ++q) {
            const float4 iv = *(const float4*)(imat + hidx * INPUT_ + q * 4);
            Irs[j][q*4+0] = kin * iv.x; Irs[j][q*4+1] = kin * iv.y;
            Irs[j][q*4+2] = kin * iv.z; Irs[j][q*4+3] = kin * iv.w;
        }
    }
    __shared__ float4 part[2][NWAVES_H_];
    __shared__ float xs[2][CH_ * INPUT_];
    const float* xb = x + (size_t)b * T_ * INPUT_;
    float* ob = out + (size_t)b * T_ * (RANK_ + INPUT_);
    {
        float4 c0 = *(const float4*)(xb + tid * 4);
        *(float4*)&xs[0][tid * 4] = c0;
    }
    float4 xstage = *(const float4*)(xb + CH_ * INPUT_ + tid * 4);
    float y = 0.0f;
    const int yoff = (tid >= 4 && tid < 20) ? (tid - 4) : 0;

    for (int t = 0; t < T_; ++t) {
        float th[EPT_];
#pragma unroll
        for (int j = 0; j < EPT_; ++j) th[j] = tanh_fast(h[j]);
        float p0 = th[0] * nr[0][0], p1 = th[0] * nr[0][1];
        float p2 = th[0] * nr[0][2], p3 = th[0] * nr[0][3];
#pragma unroll
        for (int j = 1; j < EPT_; ++j) {
            p0 = fmaf(th[j], nr[j][0], p0); p1 = fmaf(th[j], nr[j][1], p1);
            p2 = fmaf(th[j], nr[j][2], p2); p3 = fmaf(th[j], nr[j][3], p3);
        }
        DPP_ADD(p0, 0x111); DPP_ADD(p1, 0x111); DPP_ADD(p2, 0x111); DPP_ADD(p3, 0x111);
        DPP_ADD(p0, 0x112); DPP_ADD(p1, 0x112); DPP_ADD(p2, 0x112); DPP_ADD(p3, 0x112);
        DPP_ADD(p0, 0x114); DPP_ADD(p1, 0x114); DPP_ADD(p2, 0x114); DPP_ADD(p3, 0x114);
        DPP_ADD(p0, 0x118); DPP_ADD(p1, 0x118); DPP_ADD(p2, 0x118); DPP_ADD(p3, 0x118);
        DPP_ADD(p0, 0x142); DPP_ADD(p1, 0x142); DPP_ADD(p2, 0x142); DPP_ADD(p3, 0x142);
        DPP_ADD(p0, 0x143); DPP_ADD(p1, 0x143); DPP_ADD(p2, 0x143); DPP_ADD(p3, 0x143);
        if (lane == 63) part[t & 1][wave] = make_float4(p0, p1, p2, p3);
        asm volatile("s_waitcnt lgkmcnt(0)\n\ts_barrier" ::: "memory");
        if ((t & (CH_ - 1)) == 0) {
            const int c = t >> 6;
            *(float4*)&xs[(c + 1) & 1][tid * 4] = xstage;
            const int cl = (c + 2 < NCH_) ? (c + 2) : (NCH_ - 1);
            xstage = *(const float4*)(xb + cl * CH_ * INPUT_ + tid * 4);
        }
        const float* xsp = &xs[(t >> 6) & 1][(t & 63) * INPUT_];
        const float4 xa = ((const float4*)xsp)[0];
        const float4 xbv = ((const float4*)xsp)[1];
        const float4 xc = ((const float4*)xsp)[2];
        const float4 xd = ((const float4*)xsp)[3];
        const float xyv = xsp[yoff];
        const float4 q0 = part[t & 1][0];
        const float4 q1 = part[t & 1][1];
        const float4 q2 = part[t & 1][2];
        const float4 q3 = part[t & 1][3];
        float ax[EPT_];
#pragma unroll
        for (int j = 0; j < EPT_; ++j) {
            float a = xa.x * Irs[j][0];
            float c = xa.y * Irs[j][1];
            a = fmaf(xa.z, Irs[j][2], a);   c = fmaf(xa.w, Irs[j][3], c);
            a = fmaf(xbv.x, Irs[j][4], a);  c = fmaf(xbv.y, Irs[j][5], c);
            a = fmaf(xbv.z, Irs[j][6], a);  c = fmaf(xbv.w, Irs[j][7], c);
            a = fmaf(xc.x, Irs[j][8], a);   c = fmaf(xc.y, Irs[j][9], c);
            a = fmaf(xc.z, Irs[j][10], a);  c = fmaf(xc.w, Irs[j][11], c);
            a = fmaf(xd.x, Irs[j][12], a);  c = fmaf(xd.y, Irs[j][13], c);
            a = fmaf(xd.z, Irs[j][14], a);  c = fmaf(xd.w, Irs[j][15], c);
            ax[j] = a + c;
        }
        const float s0 = (q0.x + q1.x) + (q2.x + q3.x);
        const float s1 = (q0.y + q1.y) + (q2.y + q3.y);
        const float s2 = (q0.z + q1.z) + (q2.z + q3.z);
        const float s3 = (q0.w + q1.w) + (q2.w + q3.w);
#pragma unroll
        for (int j = 0; j < EPT_; ++j) {
            float a01 = fmaf(s1, mrs[j][1], fmaf(s0, mrs[j][0], ax[j]));
            float a23 = fmaf(s3, mrs[j][3], s2 * mrs[j][2]);
            h[j] = fmaf(kd, h[j], a01 + a23);
        }
        if (tid < 20) {
            float drive;
            if (tid < 4) {
                float sv = (tid == 0) ? s0 : (tid == 1) ? s1 : (tid == 2) ? s2 : s3;
                drive = krec * sv;
            } else {
                drive = kin * xyv;
            }
            y = fmaf(kd, y, drive);
            ob[t * 20 + tid] = y;
        }
    }
}

extern "C" void kernel_launch(void* const* d_in, const int* in_sizes, int n_in,
                              void* d_out, int out_size, void* d_ws, size_t ws_size,
                              hipStream_t stream) {
    const float* x    = (const float*)d_in[0];
    const float* m    = (const float*)d_in[1];
    const float* n    = (const float*)d_in[2];
    const float* imat = (const float*)d_in[3];
    float* out = (float*)d_out;

    const size_t u_bytes = (size_t)BATCH_ * T_ * HIDDEN_ * sizeof(float); // 128 MB
    if (d_ws != nullptr && ws_size >= u_bytes) {
        float* u = (float*)d_ws;
        precompute_u<<<dim3(PRE_BLOCKS_), dim3(TPB_), 0, stream>>>(x, imat, u);
        rnn_scan_kernel<<<dim3(BATCH_ / 2), dim3(SCAN_THREADS_), 0, stream>>>(x, m, n, u, out);
    } else {
        rnn_scan_fallback<<<dim3(BATCH_), dim3(TPB_), 0, stream>>>(x, m, n, imat, out);
    }
}

// Round 6
// 573.924 us; speedup vs baseline: 1.2183x; 1.2183x over previous
//
#include <hip/hip_runtime.h>
#include <math.h>

// Problem constants (MixtureLowRankRNN)
#define HIDDEN_ 1024
#define RANK_ 4
#define INPUT_ 16
#define T_ 1024
#define BATCH_ 32

// --- scan geometry: ONE batch per block, 512 threads = 8 waves = 2 waves/SIMD.
// R5 measured: 2 waves/SIMD interleave gives 1.6x per-CU throughput (708 vs
// 1126 cy/batch-step) — but R5 paid for it with half the CUs (2 batches/block).
// Here: same batch split across 8 waves -> 2/SIMD AND all 32 CUs.
#define SCAN_THREADS_ 512
#define NW_ (SCAN_THREADS_ / 64)      // 8 waves
#define EPT_ (HIDDEN_ / SCAN_THREADS_) // 2 h-elements per thread
#define CH_ 64                        // x-steps per LDS-staged chunk (4KB)
#define NCH_ (T_ / CH_)               // 16 chunks

// fallback geometry (no workspace): 256 threads, 4 elems/thread
#define FTPB_ 256
#define FEPT_ 4
#define FNW_ 4

#define PRE_BLOCKS_ 2048
#define ROWS_ (BATCH_ * T_)              // 32768 rows of x
#define PASSES_ (ROWS_ / PRE_BLOCKS_)    // 16

typedef float f32x4 __attribute__((ext_vector_type(4)));

__device__ __forceinline__ float fast_exp2(float x) {
#if defined(__has_builtin)
#if __has_builtin(__builtin_amdgcn_exp2f)
    return __builtin_amdgcn_exp2f(x);
#else
    return exp2f(x);
#endif
#else
    return exp2f(x);
#endif
}

__device__ __forceinline__ float fast_rcp(float x) {
#if defined(__has_builtin)
#if __has_builtin(__builtin_amdgcn_rcpf)
    return __builtin_amdgcn_rcpf(x);
#else
    return 1.0f / x;
#endif
#else
    return 1.0f / x;
#endif
}

// tanh(x) = 1 - 2/(exp(2x)+1); exp(2x) = 2^(2*log2(e)*x).
__device__ __forceinline__ float tanh_fast(float x) {
    float e = fast_exp2(x * 2.885390081777926815f); // 2*log2(e)
    return fmaf(-2.0f, fast_rcp(e + 1.0f), 1.0f);
}

// One DPP reduce step: v += dpp_mov(v, ctrl) with old=0, bound_ctrl=1
#define DPP_ADD(v, ctrl)                                                          \
    do {                                                                          \
        int _t = __builtin_amdgcn_update_dpp(0, __float_as_int(v), (ctrl), 0xf,   \
                                             0xf, true);                          \
        (v) += __int_as_float(_t);                                                \
    } while (0)

// ---------------------------------------------------------------------------
// Kernel 1: u[row, h] = kin * sum_i I[h,i] * x[row,i]   (row = b*T + t)
// ---------------------------------------------------------------------------
__global__ __launch_bounds__(FTPB_, 2) void precompute_u(
    const float* __restrict__ x,     // [ROWS_, 16]
    const float* __restrict__ imat,  // [H, 16]
    float* __restrict__ u)           // [ROWS_, H]
{
    const int tid = threadIdx.x;
    const int bid = blockIdx.x;
    const float kin = 0.1f;

    float Ir[4][INPUT_];
#pragma unroll
    for (int r = 0; r < 4; ++r) {
        const float* ip = imat + (4 * tid + r) * INPUT_;
#pragma unroll
        for (int q = 0; q < 4; ++q) {
            const float4 v = *(const float4*)(ip + 4 * q);
            Ir[r][q*4+0] = kin * v.x; Ir[r][q*4+1] = kin * v.y;
            Ir[r][q*4+2] = kin * v.z; Ir[r][q*4+3] = kin * v.w;
        }
    }

    for (int p = 0; p < PASSES_; ++p) {
        const int row = p * PRE_BLOCKS_ + bid;
        const float* xr = x + (size_t)row * INPUT_;
        float xv[INPUT_];
#pragma unroll
        for (int q = 0; q < 4; ++q) {
            const float4 v = ((const float4*)xr)[q];   // wave-uniform
            xv[q*4+0] = v.x; xv[q*4+1] = v.y; xv[q*4+2] = v.z; xv[q*4+3] = v.w;
        }
        float4 acc;
        float a[4];
#pragma unroll
        for (int r = 0; r < 4; ++r) {
            float s0 = xv[0] * Ir[r][0];
            float s1 = xv[1] * Ir[r][1];
#pragma unroll
            for (int i = 2; i < INPUT_; i += 2) {
                s0 = fmaf(xv[i],     Ir[r][i],     s0);
                s1 = fmaf(xv[i + 1], Ir[r][i + 1], s1);
            }
            a[r] = s0 + s1;
        }
        acc.x = a[0]; acc.y = a[1]; acc.z = a[2]; acc.w = a[3];
        *(float4*)(u + (size_t)row * HIDDEN_ + 4 * tid) = acc;  // coalesced
    }
}

// ---------------------------------------------------------------------------
// Kernel 2: serial scan — one batch per block, 512 thr (8 waves, 2/SIMD).
//   y_t = 0.9*y_{t-1} + [krec*s_t ; kin*x_t],  s_t = n^T tanh(h_{t-1}),
//   h_t = 0.9*h_{t-1} + (krec*m) s_t + u_t     (u precomputed).
// ---------------------------------------------------------------------------
__global__ __launch_bounds__(SCAN_THREADS_)
__attribute__((amdgpu_waves_per_eu(2, 2)))
void rnn_scan_kernel(
    const float* __restrict__ x,     // [B, T, 16]
    const float* __restrict__ m,     // [H, 4]
    const float* __restrict__ n,     // [H, 4]
    const float* __restrict__ u,     // [B, T, H] precomputed
    float* __restrict__ out)         // [B, T, 20]
{
    const int tid  = threadIdx.x;
    const int wv   = tid >> 6;          // wave index 0..7
    const int lane = tid & 63;
    const int b    = blockIdx.x;

    const float kd   = 0.9f;                      // 1 - ALPHA
    const float krec = 0.1f * (500.0f / 1024.0f); // ALPHA * BASE_SCALE / HIDDEN

    float h[EPT_];
    float mrs[EPT_][RANK_];    // krec * m row
    float nr[EPT_][RANK_];
#pragma unroll
    for (int j = 0; j < EPT_; ++j) {
        const int hidx = tid * EPT_ + j;
        h[j] = 0.0f;
        const float4 mv = *(const float4*)(m + hidx * RANK_);
        mrs[j][0] = krec * mv.x; mrs[j][1] = krec * mv.y;
        mrs[j][2] = krec * mv.z; mrs[j][3] = krec * mv.w;
        const float4 nv = *(const float4*)(n + hidx * RANK_);
        nr[j][0] = nv.x; nr[j][1] = nv.y; nr[j][2] = nv.z; nr[j][3] = nv.w;
    }

    // LDS: 8 cross-wave partials (parity dbuf) + staged x chunks (dbuf)
    __shared__ float4 part[2][NW_];
    __shared__ float xs[2][CH_ * INPUT_];   // 2 x 4KB

    const float* xb = x + (size_t)b * T_ * INPUT_;
    const float* ub = u + (size_t)b * T_ * HIDDEN_ + tid * EPT_;
    float* ob = out + (size_t)b * T_ * (RANK_ + INPUT_);

    // Prologue: stage x chunk 0 -> xs[0]; chunk 1 in regs (tid<256 only;
    // chunk = 1024 floats = 256 float4).
    float4 xstage = make_float4(0.f, 0.f, 0.f, 0.f);
    if (tid < 256) {
        float4 c0 = *(const float4*)(xb + tid * 4);
        *(float4*)&xs[0][tid * 4] = c0;
        xstage = *(const float4*)(xb + CH_ * INPUT_ + tid * 4);
    }

    // u prefetch, 4 steps deep (float2: this thread's 2 h-elements)
    float2 upf[4];
#pragma unroll
    for (int k = 0; k < 4; ++k)
        upf[k] = *(const float2*)(ub + (size_t)k * HIDDEN_);

    float y = 0.0f;  // output accumulator (tid < 20)
    const int yoff = (tid >= 4 && tid < 20) ? (tid - 4) : 0;

#pragma unroll 4
    for (int t = 0; t < T_; ++t) {
        // --- tanh(h) + rank partials (VALU only) ---
        float th[EPT_];
#pragma unroll
        for (int j = 0; j < EPT_; ++j) th[j] = tanh_fast(h[j]);

        float p0 = th[0] * nr[0][0], p1 = th[0] * nr[0][1];
        float p2 = th[0] * nr[0][2], p3 = th[0] * nr[0][3];
#pragma unroll
        for (int j = 1; j < EPT_; ++j) {
            p0 = fmaf(th[j], nr[j][0], p0);
            p1 = fmaf(th[j], nr[j][1], p1);
            p2 = fmaf(th[j], nr[j][2], p2);
            p3 = fmaf(th[j], nr[j][3], p3);
        }

        // --- wave reduce via DPP, level-major for ILP across 4 ranks ---
        DPP_ADD(p0, 0x111); DPP_ADD(p1, 0x111); DPP_ADD(p2, 0x111); DPP_ADD(p3, 0x111);
        DPP_ADD(p0, 0x112); DPP_ADD(p1, 0x112); DPP_ADD(p2, 0x112); DPP_ADD(p3, 0x112);
        DPP_ADD(p0, 0x114); DPP_ADD(p1, 0x114); DPP_ADD(p2, 0x114); DPP_ADD(p3, 0x114);
        DPP_ADD(p0, 0x118); DPP_ADD(p1, 0x118); DPP_ADD(p2, 0x118); DPP_ADD(p3, 0x118);
        DPP_ADD(p0, 0x142); DPP_ADD(p1, 0x142); DPP_ADD(p2, 0x142); DPP_ADD(p3, 0x142);
        DPP_ADD(p0, 0x143); DPP_ADD(p1, 0x143); DPP_ADD(p2, 0x143); DPP_ADD(p3, 0x143);

        if (lane == 63) part[t & 1][wv] = make_float4(p0, p1, p2, p3);

        // Raw barrier: LDS-visibility wait ONLY (no vmcnt drain — u prefetch,
        // x staging loads and y stores stay in flight across steps).
        asm volatile("s_waitcnt lgkmcnt(0)\n\ts_barrier" ::: "memory");

        // --- x chunk staging for the y path (every 64 steps, waves 0-3) ---
        if ((t & (CH_ - 1)) == 0) {
            if (tid < 256) {
                const int c = t >> 6;
                *(float4*)&xs[(c + 1) & 1][tid * 4] = xstage;   // chunk c+1
                const int cl = (c + 2 < NCH_) ? (c + 2) : (NCH_ - 1);
                xstage = *(const float4*)(xb + cl * CH_ * INPUT_ + tid * 4);
            }
        }

        // --- read 8 cross-wave partials (uniform-address LDS broadcast) ---
        const float4 a0 = part[t & 1][0];
        const float4 a1 = part[t & 1][1];
        const float4 a2 = part[t & 1][2];
        const float4 a3 = part[t & 1][3];
        const float4 a4 = part[t & 1][4];
        const float4 a5 = part[t & 1][5];
        const float4 a6 = part[t & 1][6];
        const float4 a7 = part[t & 1][7];
        const float xyv = xs[(t >> 6) & 1][(t & 63) * INPUT_ + yoff];

        const float2 uv = upf[t & 3];   // prefetched 4 steps ago
        {   // refill slot with u[t+4] (clamped dummy re-read near the tail)
            const int tn = (t + 4 < T_) ? (t + 4) : t;
            upf[t & 3] = *(const float2*)(ub + (size_t)tn * HIDDEN_);
        }

        // --- combine partials -> s (vector adds; pairs pack to v_pk_add) ---
        const float4 sv4 = ((a0 + a1) + (a2 + a3)) + ((a4 + a5) + (a6 + a7));
        const float s0 = sv4.x, s1 = sv4.y, s2 = sv4.z, s3 = sv4.w;

        // --- h <- kd*h + mrs@s + u_t  (short tree from s) ---
        const float uq[2] = {uv.x, uv.y};
#pragma unroll
        for (int j = 0; j < EPT_; ++j) {
            float a01 = fmaf(s1, mrs[j][1], fmaf(s0, mrs[j][0], uq[j]));
            float a23 = fmaf(s3, mrs[j][3], s2 * mrs[j][2]);
            h[j] = fmaf(kd, h[j], a01 + a23);
        }

        // --- y_t = kd*y_{t-1} + [krec*s ; kin*x_t]  (lanes 0..19 of wave 0) ---
        if (tid < 20) {
            float drive;
            if (tid < 4) {
                float sv = (tid == 0) ? s0 : (tid == 1) ? s1 : (tid == 2) ? s2 : s3;
                drive = krec * sv;
            } else {
                drive = 0.1f * xyv;   // kin
            }
            y = fmaf(kd, y, drive);
            ob[t * 20 + tid] = y;   // fire-and-forget: never drained in-loop
        }
    }
}

// ---------------------------------------------------------------------------
// Fallback (no workspace): R2-style single kernel computing I@x in-loop.
// ---------------------------------------------------------------------------
__global__ __launch_bounds__(FTPB_)
__attribute__((amdgpu_waves_per_eu(1, 1)))
void rnn_scan_fallback(
    const float* __restrict__ x, const float* __restrict__ m,
    const float* __restrict__ n, const float* __restrict__ imat,
    float* __restrict__ out)
{
    const int b    = blockIdx.x;
    const int tid  = threadIdx.x;
    const int wave = tid >> 6;
    const int lane = tid & 63;
    const float kd = 0.9f, krec = 0.1f * (500.0f / 1024.0f), kin = 0.1f;

    float h[FEPT_], mrs[FEPT_][RANK_], nr[FEPT_][RANK_], Irs[FEPT_][INPUT_];
#pragma unroll
    for (int j = 0; j < FEPT_; ++j) {
        const int hidx = tid * FEPT_ + j;
        h[j] = 0.0f;
        const float4 mv = *(const float4*)(m + hidx * RANK_);
        mrs[j][0] = krec * mv.x; mrs[j][1] = krec * mv.y;
        mrs[j][2] = krec * mv.z; mrs[j][3] = krec * mv.w;
        const float4 nv = *(const float4*)(n + hidx * RANK_);
        nr[j][0] = nv.x; nr[j][1] = nv.y; nr[j][2] = nv.z; nr[j][3] = nv.w;
#pragma unroll
        for (int q = 0; q < 4; ++q) {
            const float4 iv = *(const float4*)(imat + hidx * INPUT_ + q * 4);
            Irs[j][q*4+0] = kin * iv.x; Irs[j][q*4+1] = kin * iv.y;
            Irs[j][q*4+2] = kin * iv.z; Irs[j][q*4+3] = kin * iv.w;
        }
    }
    __shared__ float4 part[2][FNW_];
    __shared__ float xs[2][CH_ * INPUT_];
    const float* xb = x + (size_t)b * T_ * INPUT_;
    float* ob = out + (size_t)b * T_ * (RANK_ + INPUT_);
    {
        float4 c0 = *(const float4*)(xb + tid * 4);
        *(float4*)&xs[0][tid * 4] = c0;
    }
    float4 xstage = *(const float4*)(xb + CH_ * INPUT_ + tid * 4);
    float y = 0.0f;
    const int yoff = (tid >= 4 && tid < 20) ? (tid - 4) : 0;

    for (int t = 0; t < T_; ++t) {
        float th[FEPT_];
#pragma unroll
        for (int j = 0; j < FEPT_; ++j) th[j] = tanh_fast(h[j]);
        float p0 = th[0] * nr[0][0], p1 = th[0] * nr[0][1];
        float p2 = th[0] * nr[0][2], p3 = th[0] * nr[0][3];
#pragma unroll
        for (int j = 1; j < FEPT_; ++j) {
            p0 = fmaf(th[j], nr[j][0], p0); p1 = fmaf(th[j], nr[j][1], p1);
            p2 = fmaf(th[j], nr[j][2], p2); p3 = fmaf(th[j], nr[j][3], p3);
        }
        DPP_ADD(p0, 0x111); DPP_ADD(p1, 0x111); DPP_ADD(p2, 0x111); DPP_ADD(p3, 0x111);
        DPP_ADD(p0, 0x112); DPP_ADD(p1, 0x112); DPP_ADD(p2, 0x112); DPP_ADD(p3, 0x112);
        DPP_ADD(p0, 0x114); DPP_ADD(p1, 0x114); DPP_ADD(p2, 0x114); DPP_ADD(p3, 0x114);
        DPP_ADD(p0, 0x118); DPP_ADD(p1, 0x118); DPP_ADD(p2, 0x118); DPP_ADD(p3, 0x118);
        DPP_ADD(p0, 0x142); DPP_ADD(p1, 0x142); DPP_ADD(p2, 0x142); DPP_ADD(p3, 0x142);
        DPP_ADD(p0, 0x143); DPP_ADD(p1, 0x143); DPP_ADD(p2, 0x143); DPP_ADD(p3, 0x143);
        if (lane == 63) part[t & 1][wave] = make_float4(p0, p1, p2, p3);
        asm volatile("s_waitcnt lgkmcnt(0)\n\ts_barrier" ::: "memory");
        if ((t & (CH_ - 1)) == 0) {
            const int c = t >> 6;
            *(float4*)&xs[(c + 1) & 1][tid * 4] = xstage;
            const int cl = (c + 2 < NCH_) ? (c + 2) : (NCH_ - 1);
            xstage = *(const float4*)(xb + cl * CH_ * INPUT_ + tid * 4);
        }
        const float* xsp = &xs[(t >> 6) & 1][(t & 63) * INPUT_];
        const float4 xa = ((const float4*)xsp)[0];
        const float4 xbv = ((const float4*)xsp)[1];
        const float4 xc = ((const float4*)xsp)[2];
        const float4 xd = ((const float4*)xsp)[3];
        const float xyv = xsp[yoff];
        const float4 q0 = part[t & 1][0];
        const float4 q1 = part[t & 1][1];
        const float4 q2 = part[t & 1][2];
        const float4 q3 = part[t & 1][3];
        float ax[FEPT_];
#pragma unroll
        for (int j = 0; j < FEPT_; ++j) {
            float a = xa.x * Irs[j][0];
            float c = xa.y * Irs[j][1];
            a = fmaf(xa.z, Irs[j][2], a);   c = fmaf(xa.w, Irs[j][3], c);
            a = fmaf(xbv.x, Irs[j][4], a);  c = fmaf(xbv.y, Irs[j][5], c);
            a = fmaf(xbv.z, Irs[j][6], a);  c = fmaf(xbv.w, Irs[j][7], c);
            a = fmaf(xc.x, Irs[j][8], a);   c = fmaf(xc.y, Irs[j][9], c);
            a = fmaf(xc.z, Irs[j][10], a);  c = fmaf(xc.w, Irs[j][11], c);
            a = fmaf(xd.x, Irs[j][12], a);  c = fmaf(xd.y, Irs[j][13], c);
            a = fmaf(xd.z, Irs[j][14], a);  c = fmaf(xd.w, Irs[j][15], c);
            ax[j] = a + c;
        }
        const float s0 = (q0.x + q1.x) + (q2.x + q3.x);
        const float s1 = (q0.y + q1.y) + (q2.y + q3.y);
        const float s2 = (q0.z + q1.z) + (q2.z + q3.z);
        const float s3 = (q0.w + q1.w) + (q2.w + q3.w);
#pragma unroll
        for (int j = 0; j < FEPT_; ++j) {
            float a01 = fmaf(s1, mrs[j][1], fmaf(s0, mrs[j][0], ax[j]));
            float a23 = fmaf(s3, mrs[j][3], s2 * mrs[j][2]);
            h[j] = fmaf(kd, h[j], a01 + a23);
        }
        if (tid < 20) {
            float drive;
            if (tid < 4) {
                float sv = (tid == 0) ? s0 : (tid == 1) ? s1 : (tid == 2) ? s2 : s3;
                drive = krec * sv;
            } else {
                drive = kin * xyv;
            }
            y = fmaf(kd, y, drive);
            ob[t * 20 + tid] = y;
        }
    }
}

extern "C" void kernel_launch(void* const* d_in, const int* in_sizes, int n_in,
                              void* d_out, int out_size, void* d_ws, size_t ws_size,
                              hipStream_t stream) {
    const float* x    = (const float*)d_in[0];
    const float* m    = (const float*)d_in[1];
    const float* n    = (const float*)d_in[2];
    const float* imat = (const float*)d_in[3];
    float* out = (float*)d_out;

    const size_t u_bytes = (size_t)BATCH_ * T_ * HIDDEN_ * sizeof(float); // 128 MB
    if (d_ws != nullptr && ws_size >= u_bytes) {
        float* u = (float*)d_ws;
        precompute_u<<<dim3(PRE_BLOCKS_), dim3(FTPB_), 0, stream>>>(x, imat, u);
        rnn_scan_kernel<<<dim3(BATCH_), dim3(SCAN_THREADS_), 0, stream>>>(x, m, n, u, out);
    } else {
        rnn_scan_fallback<<<dim3(BATCH_), dim3(FTPB_), 0, stream>>>(x, m, n, imat, out);
    }
}

// Round 7
// 572.113 us; speedup vs baseline: 1.2221x; 1.0032x over previous
//
#include <hip/hip_runtime.h>
#include <math.h>

// Problem constants (MixtureLowRankRNN)
#define HIDDEN_ 1024
#define RANK_ 4
#define INPUT_ 16
#define T_ 1024
#define BATCH_ 32

// scan geometry: ONE batch per block, 512 threads = 8 waves = 2 waves/SIMD
#define SCAN_THREADS_ 512
#define NW_ (SCAN_THREADS_ / 64)       // 8 waves
#define EPT_ (HIDDEN_ / SCAN_THREADS_) // 2 h-elements per thread
#define CH_ 64                         // x-steps per LDS-staged chunk (4KB)
#define NCH_ (T_ / CH_)                // 16 chunks
#define UCH_ 4                         // u-steps per LDS-staged chunk (16KB)
#define NUCH_ (T_ / UCH_)              // 256 u-chunks

// fallback geometry (no workspace): 256 threads, 4 elems/thread
#define FTPB_ 256
#define FEPT_ 4
#define FNW_ 4

#define PRE_BLOCKS_ 2048
#define ROWS_ (BATCH_ * T_)              // 32768 rows of x
#define PASSES_ (ROWS_ / PRE_BLOCKS_)    // 16

__device__ __forceinline__ float fast_exp2(float x) {
#if defined(__has_builtin)
#if __has_builtin(__builtin_amdgcn_exp2f)
    return __builtin_amdgcn_exp2f(x);
#else
    return exp2f(x);
#endif
#else
    return exp2f(x);
#endif
}

__device__ __forceinline__ float fast_rcp(float x) {
#if defined(__has_builtin)
#if __has_builtin(__builtin_amdgcn_rcpf)
    return __builtin_amdgcn_rcpf(x);
#else
    return 1.0f / x;
#endif
#else
    return 1.0f / x;
#endif
}

// tanh(x) = 1 - 2/(exp(2x)+1); exp(2x) = 2^(2*log2(e)*x).
__device__ __forceinline__ float tanh_fast(float x) {
    float e = fast_exp2(x * 2.885390081777926815f); // 2*log2(e)
    return fmaf(-2.0f, fast_rcp(e + 1.0f), 1.0f);
}

// One DPP reduce step: v += dpp_mov(v, ctrl) with old=0, bound_ctrl=1
#define DPP_ADD(v, ctrl)                                                          \
    do {                                                                          \
        int _t = __builtin_amdgcn_update_dpp(0, __float_as_int(v), (ctrl), 0xf,   \
                                             0xf, true);                          \
        (v) += __int_as_float(_t);                                                \
    } while (0)

// ---------------------------------------------------------------------------
// Kernel 1: u[row, h] = kin * sum_i I[h,i] * x[row,i]   (row = b*T + t)
// ---------------------------------------------------------------------------
__global__ __launch_bounds__(FTPB_, 2) void precompute_u(
    const float* __restrict__ x,     // [ROWS_, 16]
    const float* __restrict__ imat,  // [H, 16]
    float* __restrict__ u)           // [ROWS_, H]
{
    const int tid = threadIdx.x;
    const int bid = blockIdx.x;
    const float kin = 0.1f;

    float Ir[4][INPUT_];
#pragma unroll
    for (int r = 0; r < 4; ++r) {
        const float* ip = imat + (4 * tid + r) * INPUT_;
#pragma unroll
        for (int q = 0; q < 4; ++q) {
            const float4 v = *(const float4*)(ip + 4 * q);
            Ir[r][q*4+0] = kin * v.x; Ir[r][q*4+1] = kin * v.y;
            Ir[r][q*4+2] = kin * v.z; Ir[r][q*4+3] = kin * v.w;
        }
    }

    for (int p = 0; p < PASSES_; ++p) {
        const int row = p * PRE_BLOCKS_ + bid;
        const float* xr = x + (size_t)row * INPUT_;
        float xv[INPUT_];
#pragma unroll
        for (int q = 0; q < 4; ++q) {
            const float4 v = ((const float4*)xr)[q];   // wave-uniform
            xv[q*4+0] = v.x; xv[q*4+1] = v.y; xv[q*4+2] = v.z; xv[q*4+3] = v.w;
        }
        float4 acc;
        float a[4];
#pragma unroll
        for (int r = 0; r < 4; ++r) {
            float s0 = xv[0] * Ir[r][0];
            float s1 = xv[1] * Ir[r][1];
#pragma unroll
            for (int i = 2; i < INPUT_; i += 2) {
                s0 = fmaf(xv[i],     Ir[r][i],     s0);
                s1 = fmaf(xv[i + 1], Ir[r][i + 1], s1);
            }
            a[r] = s0 + s1;
        }
        acc.x = a[0]; acc.y = a[1]; acc.z = a[2]; acc.w = a[3];
        *(float4*)(u + (size_t)row * HIDDEN_ + 4 * tid) = acc;  // coalesced
    }
}

// ---------------------------------------------------------------------------
// Kernel 2: serial scan — one batch/block, 512 thr (8 waves, 2/SIMD).
// ZERO per-step compiler-visible VMEM: u comes via 4-step LDS chunks
// (loads issued 4 steps ahead), y accumulates in LDS and is dumped every
// 64 steps. The ~700 cy/step VMEM-latency exposure (invariant across
// R0-R6: step = ~700 + issue in every config) is removed.
//   y_t = 0.9*y_{t-1} + [krec*s_t ; kin*x_t],  s_t = n^T tanh(h_{t-1}),
//   h_t = 0.9*h_{t-1} + (krec*m) s_t + u_t     (u precomputed).
// ---------------------------------------------------------------------------
__global__ __launch_bounds__(SCAN_THREADS_)
__attribute__((amdgpu_waves_per_eu(2, 2)))
void rnn_scan_kernel(
    const float* __restrict__ x,     // [B, T, 16]
    const float* __restrict__ m,     // [H, 4]
    const float* __restrict__ n,     // [H, 4]
    const float* __restrict__ u,     // [B, T, H] precomputed
    float* __restrict__ out)         // [B, T, 20]
{
    const int tid  = threadIdx.x;
    const int wv   = tid >> 6;          // wave index 0..7
    const int lane = tid & 63;
    const int b    = blockIdx.x;

    const float kd   = 0.9f;                      // 1 - ALPHA
    const float krec = 0.1f * (500.0f / 1024.0f); // ALPHA * BASE_SCALE / HIDDEN

    float h[EPT_];
    float mrs[EPT_][RANK_];    // krec * m row
    float nr[EPT_][RANK_];
#pragma unroll
    for (int j = 0; j < EPT_; ++j) {
        const int hidx = tid * EPT_ + j;
        h[j] = 0.0f;
        const float4 mv = *(const float4*)(m + hidx * RANK_);
        mrs[j][0] = krec * mv.x; mrs[j][1] = krec * mv.y;
        mrs[j][2] = krec * mv.z; mrs[j][3] = krec * mv.w;
        const float4 nv = *(const float4*)(n + hidx * RANK_);
        nr[j][0] = nv.x; nr[j][1] = nv.y; nr[j][2] = nv.z; nr[j][3] = nv.w;
    }

    // LDS: partials dbuf + x-chunk dbuf + u-chunk dbuf + y-chunk dbuf
    __shared__ float4 part[2][NW_];             // 256 B
    __shared__ float xs[2][CH_ * INPUT_];       // 8 KB
    __shared__ float us[2][UCH_ * HIDDEN_];     // 32 KB
    __shared__ float ys[2][CH_ * 20];           // 10 KB

    const float* xb  = x + (size_t)b * T_ * INPUT_;
    const float* ub0 = u + (size_t)b * T_ * HIDDEN_;
    float* ob = out + (size_t)b * T_ * (RANK_ + INPUT_);

    // ---- prologue staging ----
    // x chunk 0 -> xs[0]; chunk 1 into regs (tid<256: 256 float4 = 4KB).
    float4 xstage = make_float4(0.f, 0.f, 0.f, 0.f);
    if (tid < 256) {
        float4 c0 = *(const float4*)(xb + tid * 4);
        *(float4*)&xs[0][tid * 4] = c0;
        xstage = *(const float4*)(xb + CH_ * INPUT_ + tid * 4);
    }
    // u chunk 0 -> us[0] (4096 floats: 8 per thread); chunk 1 into regs.
    {
        float4 a0 = *(const float4*)(ub0 + tid * 8);
        float4 a1 = *(const float4*)(ub0 + tid * 8 + 4);
        *(float4*)&us[0][tid * 8]     = a0;
        *(float4*)&us[0][tid * 8 + 4] = a1;
    }
    float4 ust0 = *(const float4*)(ub0 + UCH_ * HIDDEN_ + tid * 8);
    float4 ust1 = *(const float4*)(ub0 + UCH_ * HIDDEN_ + tid * 8 + 4);

    __syncthreads();   // make xs[0]/us[0] visible before the loop

    float y = 0.0f;  // output accumulator (tid < 20)
    const int yoff = (tid >= 4 && tid < 20) ? (tid - 4) : 0;

#pragma unroll 4
    for (int t = 0; t < T_; ++t) {
        // --- tanh(h) + rank partials (VALU only) ---
        float th[EPT_];
#pragma unroll
        for (int j = 0; j < EPT_; ++j) th[j] = tanh_fast(h[j]);

        float p0 = th[0] * nr[0][0], p1 = th[0] * nr[0][1];
        float p2 = th[0] * nr[0][2], p3 = th[0] * nr[0][3];
#pragma unroll
        for (int j = 1; j < EPT_; ++j) {
            p0 = fmaf(th[j], nr[j][0], p0);
            p1 = fmaf(th[j], nr[j][1], p1);
            p2 = fmaf(th[j], nr[j][2], p2);
            p3 = fmaf(th[j], nr[j][3], p3);
        }

        // --- wave reduce via DPP, level-major for ILP across 4 ranks ---
        DPP_ADD(p0, 0x111); DPP_ADD(p1, 0x111); DPP_ADD(p2, 0x111); DPP_ADD(p3, 0x111);
        DPP_ADD(p0, 0x112); DPP_ADD(p1, 0x112); DPP_ADD(p2, 0x112); DPP_ADD(p3, 0x112);
        DPP_ADD(p0, 0x114); DPP_ADD(p1, 0x114); DPP_ADD(p2, 0x114); DPP_ADD(p3, 0x114);
        DPP_ADD(p0, 0x118); DPP_ADD(p1, 0x118); DPP_ADD(p2, 0x118); DPP_ADD(p3, 0x118);
        DPP_ADD(p0, 0x142); DPP_ADD(p1, 0x142); DPP_ADD(p2, 0x142); DPP_ADD(p3, 0x142);
        DPP_ADD(p0, 0x143); DPP_ADD(p1, 0x143); DPP_ADD(p2, 0x143); DPP_ADD(p3, 0x143);

        if (lane == 63) part[t & 1][wv] = make_float4(p0, p1, p2, p3);

        // Raw barrier: per-wave lgkm drain + sync. No vmcnt drain — staged
        // global loads and y-dump stores stay in flight across steps.
        asm volatile("s_waitcnt lgkmcnt(0)\n\ts_barrier" ::: "memory");

        // --- u chunk staging (every 4 steps): write regs->LDS, load next ---
        if ((t & (UCH_ - 1)) == 0) {
            const int c = t >> 2;
            float* du = &us[(c + 1) & 1][0];
            *(float4*)&du[tid * 8]     = ust0;
            *(float4*)&du[tid * 8 + 4] = ust1;
            const int cl = (c + 2 < NUCH_) ? (c + 2) : (NUCH_ - 1);
            ust0 = *(const float4*)(ub0 + (size_t)cl * UCH_ * HIDDEN_ + tid * 8);
            ust1 = *(const float4*)(ub0 + (size_t)cl * UCH_ * HIDDEN_ + tid * 8 + 4);
        }

        // --- x chunk staging (every 64 steps) ---
        if ((t & (CH_ - 1)) == 0) {
            if (tid < 256) {
                const int c = t >> 6;
                *(float4*)&xs[(c + 1) & 1][tid * 4] = xstage;   // chunk c+1
                const int cl = (c + 2 < NCH_) ? (c + 2) : (NCH_ - 1);
                xstage = *(const float4*)(xb + cl * CH_ * INPUT_ + tid * 4);
            }
            // --- y dump for the previous 64-step chunk (coalesced) ---
            if (t != 0) {
                const int tc = (t >> 6) - 1;
                const float* src = &ys[tc & 1][0];
                float* dst = ob + (size_t)tc * (CH_ * 20);
                dst[tid]       = src[tid];
                dst[tid + 512] = src[tid + 512];
                if (tid < 256) dst[tid + 1024] = src[tid + 1024];
            }
        }

        // --- issue all LDS reads together (latencies overlap) ---
        const float4 a0 = part[t & 1][0];
        const float4 a1 = part[t & 1][1];
        const float4 a2 = part[t & 1][2];
        const float4 a3 = part[t & 1][3];
        const float4 a4 = part[t & 1][4];
        const float4 a5 = part[t & 1][5];
        const float4 a6 = part[t & 1][6];
        const float4 a7 = part[t & 1][7];
        const float xyv = xs[(t >> 6) & 1][(t & 63) * INPUT_ + yoff];
        const float2 uv = *(const float2*)&us[(t >> 2) & 1][(t & 3) * HIDDEN_ + tid * EPT_];

        // --- combine partials -> s (packs to v_pk_add_f32) ---
        const float4 sv4 = ((a0 + a1) + (a2 + a3)) + ((a4 + a5) + (a6 + a7));
        const float s0 = sv4.x, s1 = sv4.y, s2 = sv4.z, s3 = sv4.w;

        // --- h <- kd*h + mrs@s + u_t  (short tree from s) ---
        const float uq[2] = {uv.x, uv.y};
#pragma unroll
        for (int j = 0; j < EPT_; ++j) {
            float a01 = fmaf(s1, mrs[j][1], fmaf(s0, mrs[j][0], uq[j]));
            float a23 = fmaf(s3, mrs[j][3], s2 * mrs[j][2]);
            h[j] = fmaf(kd, h[j], a01 + a23);
        }

        // --- y_t = kd*y_{t-1} + [krec*s ; kin*x_t] -> LDS (no global store) ---
        if (tid < 20) {
            float drive;
            if (tid < 4) {
                float sv = (tid == 0) ? s0 : (tid == 1) ? s1 : (tid == 2) ? s2 : s3;
                drive = krec * sv;
            } else {
                drive = 0.1f * xyv;   // kin
            }
            y = fmaf(kd, y, drive);
            ys[(t >> 6) & 1][(t & 63) * 20 + tid] = y;
        }
    }

    // --- final y dump (chunk 15) ---
    asm volatile("s_waitcnt lgkmcnt(0)\n\ts_barrier" ::: "memory");
    {
        const int tc = NCH_ - 1;
        const float* src = &ys[tc & 1][0];
        float* dst = ob + (size_t)tc * (CH_ * 20);
        dst[tid]       = src[tid];
        dst[tid + 512] = src[tid + 512];
        if (tid < 256) dst[tid + 1024] = src[tid + 1024];
    }
}

// ---------------------------------------------------------------------------
// Fallback (no workspace): R2-style single kernel computing I@x in-loop.
// ---------------------------------------------------------------------------
__global__ __launch_bounds__(FTPB_)
__attribute__((amdgpu_waves_per_eu(1, 1)))
void rnn_scan_fallback(
    const float* __restrict__ x, const float* __restrict__ m,
    const float* __restrict__ n, const float* __restrict__ imat,
    float* __restrict__ out)
{
    const int b    = blockIdx.x;
    const int tid  = threadIdx.x;
    const int wave = tid >> 6;
    const int lane = tid & 63;
    const float kd = 0.9f, krec = 0.1f * (500.0f / 1024.0f), kin = 0.1f;

    float h[FEPT_], mrs[FEPT_][RANK_], nr[FEPT_][RANK_], Irs[FEPT_][INPUT_];
#pragma unroll
    for (int j = 0; j < FEPT_; ++j) {
        const int hidx = tid * FEPT_ + j;
        h[j] = 0.0f;
        const float4 mv = *(const float4*)(m + hidx * RANK_);
        mrs[j][0] = krec * mv.x; mrs[j][1] = krec * mv.y;
        mrs[j][2] = krec * mv.z; mrs[j][3] = krec * mv.w;
        const float4 nv = *(const float4*)(n + hidx * RANK_);
        nr[j][0] = nv.x; nr[j][1] = nv.y; nr[j][2] = nv.z; nr[j][3] = nv.w;
#pragma unroll
        for (int q = 0; q < 4; ++q) {
            const float4 iv = *(const float4*)(imat + hidx * INPUT_ + q * 4);
            Irs[j][q*4+0] = kin * iv.x; Irs[j][q*4+1] = kin * iv.y;
            Irs[j][q*4+2] = kin * iv.z; Irs[j][q*4+3] = kin * iv.w;
        }
    }
    __shared__ float4 part[2][FNW_];
    __shared__ float xs[2][CH_ * INPUT_];
    const float* xb = x + (size_t)b * T_ * INPUT_;
    float* ob = out + (size_t)b * T_ * (RANK_ + INPUT_);
    {
        float4 c0 = *(const float4*)(xb + tid * 4);
        *(float4*)&xs[0][tid * 4] = c0;
    }
    float4 xstage = *(const float4*)(xb + CH_ * INPUT_ + tid * 4);
    float y = 0.0f;
    const int yoff = (tid >= 4 && tid < 20) ? (tid - 4) : 0;

    for (int t = 0; t < T_; ++t) {
        float th[FEPT_];
#pragma unroll
        for (int j = 0; j < FEPT_; ++j) th[j] = tanh_fast(h[j]);
        float p0 = th[0] * nr[0][0], p1 = th[0] * nr[0][1];
        float p2 = th[0] * nr[0][2], p3 = th[0] * nr[0][3];
#pragma unroll
        for (int j = 1; j < FEPT_; ++j) {
            p0 = fmaf(th[j], nr[j][0], p0); p1 = fmaf(th[j], nr[j][1], p1);
            p2 = fmaf(th[j], nr[j][2], p2); p3 = fmaf(th[j], nr[j][3], p3);
        }
        DPP_ADD(p0, 0x111); DPP_ADD(p1, 0x111); DPP_ADD(p2, 0x111); DPP_ADD(p3, 0x111);
        DPP_ADD(p0, 0x112); DPP_ADD(p1, 0x112); DPP_ADD(p2, 0x112); DPP_ADD(p3, 0x112);
        DPP_ADD(p0, 0x114); DPP_ADD(p1, 0x114); DPP_ADD(p2, 0x114); DPP_ADD(p3, 0x114);
        DPP_ADD(p0, 0x118); DPP_ADD(p1, 0x118); DPP_ADD(p2, 0x118); DPP_ADD(p3, 0x118);
        DPP_ADD(p0, 0x142); DPP_ADD(p1, 0x142); DPP_ADD(p2, 0x142); DPP_ADD(p3, 0x142);
        DPP_ADD(p0, 0x143); DPP_ADD(p1, 0x143); DPP_ADD(p2, 0x143); DPP_ADD(p3, 0x143);
        if (lane == 63) part[t & 1][wave] = make_float4(p0, p1, p2, p3);
        asm volatile("s_waitcnt lgkmcnt(0)\n\ts_barrier" ::: "memory");
        if ((t & (CH_ - 1)) == 0) {
            const int c = t >> 6;
            *(float4*)&xs[(c + 1) & 1][tid * 4] = xstage;
            const int cl = (c + 2 < NCH_) ? (c + 2) : (NCH_ - 1);
            xstage = *(const float4*)(xb + cl * CH_ * INPUT_ + tid * 4);
        }
        const float* xsp = &xs[(t >> 6) & 1][(t & 63) * INPUT_];
        const float4 xa = ((const float4*)xsp)[0];
        const float4 xbv = ((const float4*)xsp)[1];
        const float4 xc = ((const float4*)xsp)[2];
        const float4 xd = ((const float4*)xsp)[3];
        const float xyv = xsp[yoff];
        const float4 q0 = part[t & 1][0];
        const float4 q1 = part[t & 1][1];
        const float4 q2 = part[t & 1][2];
        const float4 q3 = part[t & 1][3];
        float ax[FEPT_];
#pragma unroll
        for (int j = 0; j < FEPT_; ++j) {
            float a = xa.x * Irs[j][0];
            float c = xa.y * Irs[j][1];
            a = fmaf(xa.z, Irs[j][2], a);   c = fmaf(xa.w, Irs[j][3], c);
            a = fmaf(xbv.x, Irs[j][4], a);  c = fmaf(xbv.y, Irs[j][5], c);
            a = fmaf(xbv.z, Irs[j][6], a);  c = fmaf(xbv.w, Irs[j][7], c);
            a = fmaf(xc.x, Irs[j][8], a);   c = fmaf(xc.y, Irs[j][9], c);
            a = fmaf(xc.z, Irs[j][10], a);  c = fmaf(xc.w, Irs[j][11], c);
            a = fmaf(xd.x, Irs[j][12], a);  c = fmaf(xd.y, Irs[j][13], c);
            a = fmaf(xd.z, Irs[j][14], a);  c = fmaf(xd.w, Irs[j][15], c);
            ax[j] = a + c;
        }
        const float s0 = (q0.x + q1.x) + (q2.x + q3.x);
        const float s1 = (q0.y + q1.y) + (q2.y + q3.y);
        const float s2 = (q0.z + q1.z) + (q2.z + q3.z);
        const float s3 = (q0.w + q1.w) + (q2.w + q3.w);
#pragma unroll
        for (int j = 0; j < FEPT_; ++j) {
            float a01 = fmaf(s1, mrs[j][1], fmaf(s0, mrs[j][0], ax[j]));
            float a23 = fmaf(s3, mrs[j][3], s2 * mrs[j][2]);
            h[j] = fmaf(kd, h[j], a01 + a23);
        }
        if (tid < 20) {
            float drive;
            if (tid < 4) {
                float sv = (tid == 0) ? s0 : (tid == 1) ? s1 : (tid == 2) ? s2 : s3;
                drive = krec * sv;
            } else {
                drive = kin * xyv;
            }
            y = fmaf(kd, y, drive);
            ob[t * 20 + tid] = y;
        }
    }
}

extern "C" void kernel_launch(void* const* d_in, const int* in_sizes, int n_in,
                              void* d_out, int out_size, void* d_ws, size_t ws_size,
                              hipStream_t stream) {
    const float* x    = (const float*)d_in[0];
    const float* m    = (const float*)d_in[1];
    const float* n    = (const float*)d_in[2];
    const float* imat = (const float*)d_in[3];
    float* out = (float*)d_out;

    const size_t u_bytes = (size_t)BATCH_ * T_ * HIDDEN_ * sizeof(float); // 128 MB
    if (d_ws != nullptr && ws_size >= u_bytes) {
        float* u = (float*)d_ws;
        precompute_u<<<dim3(PRE_BLOCKS_), dim3(FTPB_), 0, stream>>>(x, imat, u);
        rnn_scan_kernel<<<dim3(BATCH_), dim3(SCAN_THREADS_), 0, stream>>>(x, m, n, u, out);
    } else {
        rnn_scan_fallback<<<dim3(BATCH_), dim3(FTPB_), 0, stream>>>(x, m, n, imat, out);
    }
}

// Round 8
// 519.593 us; speedup vs baseline: 1.3457x; 1.1011x over previous
//
#include <hip/hip_runtime.h>
#include <math.h>

// Problem constants (MixtureLowRankRNN)
#define HIDDEN_ 1024
#define RANK_ 4
#define INPUT_ 16
#define T_ 1024
#define BATCH_ 32

// Fused geometry: 512 threads = 8 waves.
//   waves 0-3 (tid 0-255)  : scan group, EPT=4 h-elements/thread
//   waves 4-7 (tid 256-511): helper group, computes ax(t+1)=kin*I@x(t+1),
//                            x staging, y output
// Wave i -> SIMD i&3, so each SIMD hosts exactly one scan + one helper wave;
// helper issue fills the scan wave's barrier/LDS-latency stalls (R5 mechanism).
#define NT_ 512
#define SCANT_ 256
#define EPT_ 4
#define CH_ 64                  // x-steps per staged chunk (4KB)
#define NCH_ (T_ / CH_)         // 16 chunks

__device__ __forceinline__ float fast_exp2(float x) {
#if defined(__has_builtin)
#if __has_builtin(__builtin_amdgcn_exp2f)
    return __builtin_amdgcn_exp2f(x);
#else
    return exp2f(x);
#endif
#else
    return exp2f(x);
#endif
}

__device__ __forceinline__ float fast_rcp(float x) {
#if defined(__has_builtin)
#if __has_builtin(__builtin_amdgcn_rcpf)
    return __builtin_amdgcn_rcpf(x);
#else
    return 1.0f / x;
#endif
#else
    return 1.0f / x;
#endif
}

// tanh(x) = 1 - 2/(exp(2x)+1); exp(2x) = 2^(2*log2(e)*x).
__device__ __forceinline__ float tanh_fast(float x) {
    float e = fast_exp2(x * 2.885390081777926815f); // 2*log2(e)
    return fmaf(-2.0f, fast_rcp(e + 1.0f), 1.0f);
}

// One DPP reduce step: v += dpp_mov(v, ctrl) with old=0, bound_ctrl=1
#define DPP_ADD(v, ctrl)                                                          \
    do {                                                                          \
        int _t = __builtin_amdgcn_update_dpp(0, __float_as_int(v), (ctrl), 0xf,   \
                                             0xf, true);                          \
        (v) += __int_as_float(_t);                                                \
    } while (0)

// ---------------------------------------------------------------------------
// Single fused kernel. One batch per block.
//   s_t = n^T tanh(h_{t-1})                        (scan waves, DPP+LDS reduce)
//   h_t = kd*h_{t-1} + (krec*m) s_t + ax_t          (scan waves)
//   ax_t = kin * I @ x_t                            (helper waves, 1 step ahead,
//                                                    depth-4 LDS ring)
//   y_t = kd*y_{t-1} + [krec*s_t ; kin*x_t]         (helper wave 4, lanes 0-19)
//
// axs ring depth 4 is required: with the single mid-step barrier, a depth-2
// ring has scan's read (iter t, post-barrier t) and helper's write (iter t+1,
// pre-barrier t+1) in the same barrier interval -> race. Depth 4 puts >=2
// barriers between every read and the next write of a slot.
// ---------------------------------------------------------------------------
__global__ __launch_bounds__(NT_)
__attribute__((amdgpu_waves_per_eu(2, 2)))
void rnn_fused_kernel(
    const float* __restrict__ x,     // [B, T, 16]
    const float* __restrict__ m,     // [H, 4]
    const float* __restrict__ n,     // [H, 4]
    const float* __restrict__ imat,  // [H, 16]
    float* __restrict__ out)         // [B, T, 20]
{
    const int tid  = threadIdx.x;
    const int lane = tid & 63;
    const int b    = blockIdx.x;
    const bool is_scan = (tid < SCANT_);

    const float kd   = 0.9f;                      // 1 - ALPHA
    const float krec = 0.1f * (500.0f / 1024.0f); // ALPHA * BASE_SCALE / HIDDEN
    const float kin  = 0.1f;                      // ALPHA

    __shared__ float4 part[2][SCANT_ / 64];   // 128 B  (4 wave partials, parity)
    __shared__ float  axs[4][HIDDEN_];        // 16 KB  (ax ring, depth 4)
    __shared__ float  xs[2][CH_ * INPUT_];    // 8 KB   (x chunks, parity)

    const float* xb = x + (size_t)b * T_ * INPUT_;
    float* ob = out + (size_t)b * T_ * (RANK_ + INPUT_);

    // scan-group state
    float h[EPT_];
    float mrs[EPT_][RANK_];    // krec * m row
    float nr[EPT_][RANK_];
    // helper-group state
    float Irs[EPT_][INPUT_];   // kin * I row
    float4 xstage = make_float4(0.f, 0.f, 0.f, 0.f);
    float y = 0.0f;
    int yoff = 0;

    if (is_scan) {
#pragma unroll
        for (int j = 0; j < EPT_; ++j) {
            const int hidx = tid * EPT_ + j;
            h[j] = 0.0f;
            const float4 mv = *(const float4*)(m + hidx * RANK_);
            mrs[j][0] = krec * mv.x; mrs[j][1] = krec * mv.y;
            mrs[j][2] = krec * mv.z; mrs[j][3] = krec * mv.w;
            const float4 nv = *(const float4*)(n + hidx * RANK_);
            nr[j][0] = nv.x; nr[j][1] = nv.y; nr[j][2] = nv.z; nr[j][3] = nv.w;
        }
    } else {
        const int tH = tid - SCANT_;
        yoff = (tH >= 4 && tH < 20) ? (tH - 4) : 0;
#pragma unroll
        for (int j = 0; j < EPT_; ++j) {
            const int hidx = tH * EPT_ + j;
#pragma unroll
            for (int q = 0; q < 4; ++q) {
                const float4 iv = *(const float4*)(imat + hidx * INPUT_ + q * 4);
                Irs[j][q*4+0] = kin * iv.x; Irs[j][q*4+1] = kin * iv.y;
                Irs[j][q*4+2] = kin * iv.z; Irs[j][q*4+3] = kin * iv.w;
            }
        }
        // x chunk 0 -> xs[0]; chunk 1 -> regs (256 helper thr x float4 = 4KB)
        float4 c0 = *(const float4*)(xb + tH * 4);
        *(float4*)&xs[0][tH * 4] = c0;
        xstage = *(const float4*)(xb + CH_ * INPUT_ + tH * 4);
        // ax(0) -> axs[0] (x(0) read straight from global, wave-uniform)
        float xv[INPUT_];
#pragma unroll
        for (int q = 0; q < 4; ++q) {
            const float4 v = ((const float4*)xb)[q];
            xv[q*4+0] = v.x; xv[q*4+1] = v.y; xv[q*4+2] = v.z; xv[q*4+3] = v.w;
        }
        float av[EPT_];
#pragma unroll
        for (int j = 0; j < EPT_; ++j) {
            float a = xv[0] * Irs[j][0];
            float c = xv[1] * Irs[j][1];
#pragma unroll
            for (int i = 2; i < INPUT_; i += 2) {
                a = fmaf(xv[i],     Irs[j][i],     a);
                c = fmaf(xv[i + 1], Irs[j][i + 1], c);
            }
            av[j] = a + c;
        }
        *(float4*)&axs[0][tH * 4] = make_float4(av[0], av[1], av[2], av[3]);
    }
    __syncthreads();   // xs[0]/axs[0] visible to everyone

    for (int t = 0; t < T_; ++t) {
        // ================= pre-barrier phase =================
        if (is_scan) {
            // tanh(h) + rank partials
            float th[EPT_];
#pragma unroll
            for (int j = 0; j < EPT_; ++j) th[j] = tanh_fast(h[j]);

            float p0 = th[0] * nr[0][0], p1 = th[0] * nr[0][1];
            float p2 = th[0] * nr[0][2], p3 = th[0] * nr[0][3];
#pragma unroll
            for (int j = 1; j < EPT_; ++j) {
                p0 = fmaf(th[j], nr[j][0], p0);
                p1 = fmaf(th[j], nr[j][1], p1);
                p2 = fmaf(th[j], nr[j][2], p2);
                p3 = fmaf(th[j], nr[j][3], p3);
            }

            // wave reduce via DPP, level-major for ILP across 4 ranks
            DPP_ADD(p0, 0x111); DPP_ADD(p1, 0x111); DPP_ADD(p2, 0x111); DPP_ADD(p3, 0x111);
            DPP_ADD(p0, 0x112); DPP_ADD(p1, 0x112); DPP_ADD(p2, 0x112); DPP_ADD(p3, 0x112);
            DPP_ADD(p0, 0x114); DPP_ADD(p1, 0x114); DPP_ADD(p2, 0x114); DPP_ADD(p3, 0x114);
            DPP_ADD(p0, 0x118); DPP_ADD(p1, 0x118); DPP_ADD(p2, 0x118); DPP_ADD(p3, 0x118);
            DPP_ADD(p0, 0x142); DPP_ADD(p1, 0x142); DPP_ADD(p2, 0x142); DPP_ADD(p3, 0x142);
            DPP_ADD(p0, 0x143); DPP_ADD(p1, 0x143); DPP_ADD(p2, 0x143); DPP_ADD(p3, 0x143);

            if (lane == 63) part[t & 1][tid >> 6] = make_float4(p0, p1, p2, p3);
        } else {
            // helper: ax(t+1) from staged x, into ring slot (t+1)&3
            const int tH = tid - SCANT_;
            const int tn = (t + 1 < T_) ? (t + 1) : (T_ - 1);
            const float* xsp = &xs[(tn >> 6) & 1][(tn & 63) * INPUT_];
            const float4 xa  = ((const float4*)xsp)[0];
            const float4 xb4 = ((const float4*)xsp)[1];
            const float4 xc  = ((const float4*)xsp)[2];
            const float4 xd  = ((const float4*)xsp)[3];
            float av[EPT_];
#pragma unroll
            for (int j = 0; j < EPT_; ++j) {
                float a = xa.x * Irs[j][0];
                float c = xa.y * Irs[j][1];
                a = fmaf(xa.z,  Irs[j][2],  a);  c = fmaf(xa.w,  Irs[j][3],  c);
                a = fmaf(xb4.x, Irs[j][4],  a);  c = fmaf(xb4.y, Irs[j][5],  c);
                a = fmaf(xb4.z, Irs[j][6],  a);  c = fmaf(xb4.w, Irs[j][7],  c);
                a = fmaf(xc.x,  Irs[j][8],  a);  c = fmaf(xc.y,  Irs[j][9],  c);
                a = fmaf(xc.z,  Irs[j][10], a);  c = fmaf(xc.w,  Irs[j][11], c);
                a = fmaf(xd.x,  Irs[j][12], a);  c = fmaf(xd.y,  Irs[j][13], c);
                a = fmaf(xd.z,  Irs[j][14], a);  c = fmaf(xd.w,  Irs[j][15], c);
                av[j] = a + c;
            }
            *(float4*)&axs[(t + 1) & 3][tH * 4] =
                make_float4(av[0], av[1], av[2], av[3]);
        }

        // Raw barrier: per-wave lgkm drain + sync. No vmcnt drain — x staging
        // loads and y stores stay in flight across steps.
        asm volatile("s_waitcnt lgkmcnt(0)\n\ts_barrier" ::: "memory");

        // ================= post-barrier phase =================
        if (is_scan) {
            const float4 q0 = part[t & 1][0];
            const float4 q1 = part[t & 1][1];
            const float4 q2 = part[t & 1][2];
            const float4 q3 = part[t & 1][3];
            const float4 axv = *(const float4*)&axs[t & 3][tid * 4];

            const float4 sv = (q0 + q1) + (q2 + q3);
            const float s0 = sv.x, s1 = sv.y, s2 = sv.z, s3 = sv.w;
            const float aq[EPT_] = {axv.x, axv.y, axv.z, axv.w};
#pragma unroll
            for (int j = 0; j < EPT_; ++j) {
                float a01 = fmaf(s1, mrs[j][1], fmaf(s0, mrs[j][0], aq[j]));
                float a23 = fmaf(s3, mrs[j][3], s2 * mrs[j][2]);
                h[j] = fmaf(kd, h[j], a01 + a23);
            }
        } else {
            const int tH = tid - SCANT_;
            // x chunk staging every 64 steps (writes the buffer not in use)
            if ((t & (CH_ - 1)) == 0) {
                const int c = t >> 6;
                *(float4*)&xs[(c + 1) & 1][tH * 4] = xstage;   // chunk c+1
                const int cl = (c + 2 < NCH_) ? (c + 2) : (NCH_ - 1);
                xstage = *(const float4*)(xb + cl * CH_ * INPUT_ + tH * 4);
            }
            // y path: lanes 0-19 of helper wave 4
            if (tH < 20) {
                const float4 q0 = part[t & 1][0];
                const float4 q1 = part[t & 1][1];
                const float4 q2 = part[t & 1][2];
                const float4 q3 = part[t & 1][3];
                const float4 sv = (q0 + q1) + (q2 + q3);
                float drive;
                if (tH < 4) {
                    const float svv = (tH == 0) ? sv.x : (tH == 1) ? sv.y
                                    : (tH == 2) ? sv.z : sv.w;
                    drive = krec * svv;
                } else {
                    drive = kin * xs[(t >> 6) & 1][(t & 63) * INPUT_ + yoff];
                }
                y = fmaf(kd, y, drive);
                ob[t * 20 + tH] = y;   // fire-and-forget global store
            }
        }
    }
}

extern "C" void kernel_launch(void* const* d_in, const int* in_sizes, int n_in,
                              void* d_out, int out_size, void* d_ws, size_t ws_size,
                              hipStream_t stream) {
    const float* x    = (const float*)d_in[0];
    const float* m    = (const float*)d_in[1];
    const float* n    = (const float*)d_in[2];
    const float* imat = (const float*)d_in[3];
    float* out = (float*)d_out;

    rnn_fused_kernel<<<dim3(BATCH_), dim3(NT_), 0, stream>>>(x, m, n, imat, out);
}